// Round 1
// baseline (568.702 us; speedup 1.0000x reference)
//
#include <hip/hip_runtime.h>
#include <hip/hip_bf16.h>
#include <stdint.h>

// Problem constants
constexpr int BB = 4, TT = 2048, CC = 1024, HH = 16, DD = 64;

typedef __bf16 bf16_t;
typedef bf16_t bf16x8 __attribute__((ext_vector_type(8)));
typedef float f32x4 __attribute__((ext_vector_type(4)));

__device__ __forceinline__ unsigned short f2bf(float f) {
    union { float f; unsigned int u; } v; v.f = f;
    unsigned int u = v.u;
    unsigned int r = u + 0x7fffu + ((u >> 16) & 1u);
    return (unsigned short)(r >> 16);
}

__device__ __forceinline__ f32x4 mfma16(bf16x8 a, bf16x8 b, f32x4 c) {
    return __builtin_amdgcn_mfma_f32_16x16x32_bf16(a, b, c, 0, 0, 0);
}

#define LOAD_LDS16(g, l)                                                      \
    __builtin_amdgcn_global_load_lds(                                         \
        (const __attribute__((address_space(1))) void*)(g),                   \
        (__attribute__((address_space(3))) void*)(l), 16, 0, 0)

// ---------------- f32 -> bf16 convert (n % 4 == 0) ----------------
__global__ __launch_bounds__(256) void cvt_bf16(const float* __restrict__ in,
                                                unsigned short* __restrict__ out,
                                                long n) {
    long i = ((long)blockIdx.x * blockDim.x + threadIdx.x) * 4;
    long stride = (long)gridDim.x * blockDim.x * 4;
    for (; i < n; i += stride) {
        float4 v = *(const float4*)(in + i);
        ushort4 o;
        o.x = f2bf(v.x); o.y = f2bf(v.y); o.z = f2bf(v.z); o.w = f2bf(v.w);
        *(ushort4*)(out + i) = o;
    }
}

// ---------------- GEMM: C[m,n] = sum_k A[m,k]*Bw[n,k] + bias[n] ----------------
// m97 structure: 128x128 tile, BK=32, 4 waves, global_load_lds(16B), dbuf LDS.
// MODE 0: QKV epilogue -> scatter q(B,H,T,D)*0.125, k(B,H,T,D), v^T(B,H,D,T) bf16
// MODE 1: f32 out[m*N+n]
template <int MODE>
__global__ __launch_bounds__(256, 2) void gemm_bt(
    const unsigned short* __restrict__ A,    // [M][K] bf16
    const unsigned short* __restrict__ Bw,   // [N][K] bf16
    const float* __restrict__ bias,          // [N]
    unsigned short* __restrict__ qb, unsigned short* __restrict__ kb,
    unsigned short* __restrict__ vtb, float* __restrict__ outf,
    int M, int N, int K) {
    __shared__ unsigned short As[2][128 * 32];
    __shared__ unsigned short Bs[2][128 * 32];
    const int tid = threadIdx.x;
    const int w = tid >> 6, lane = tid & 63;
    const int g = lane >> 4, q16 = lane & 15;
    const int wr = w >> 1, wc = w & 1;
    const int mbase = blockIdx.x * 128;
    const int nbase = blockIdx.y * 128;
    const int srow = lane >> 2;        // staging: row within 16-row issue
    const int scol = (lane & 3) * 8;   // staging: col (elements)

    f32x4 acc[4][4];
#pragma unroll
    for (int i = 0; i < 4; ++i)
#pragma unroll
        for (int j = 0; j < 4; ++j) acc[i][j] = (f32x4){0.f, 0.f, 0.f, 0.f};

    const int nk = K >> 5;

    auto stage = [&](int buf, int t) {
        const int k0 = t << 5;
#pragma unroll
        for (int ii = 0; ii < 2; ++ii) {
            const int i = w + ii * 4;  // issue index 0..7
            const unsigned short* ga =
                A + (long)(mbase + i * 16 + srow) * K + k0 + scol;
            LOAD_LDS16(ga, &As[buf][i * 512]);
            const unsigned short* gb =
                Bw + (long)(nbase + i * 16 + srow) * K + k0 + scol;
            LOAD_LDS16(gb, &Bs[buf][i * 512]);
        }
    };

    stage(0, 0);
    __syncthreads();
    int cur = 0;
    for (int t = 0; t < nk; ++t) {
        if (t + 1 < nk) stage(cur ^ 1, t + 1);
        bf16x8 af[4], bfr[4];
#pragma unroll
        for (int mi = 0; mi < 4; ++mi)
            af[mi] = *(const bf16x8*)&As[cur][(wr * 64 + mi * 16 + q16) * 32 + 8 * g];
#pragma unroll
        for (int ni = 0; ni < 4; ++ni)
            bfr[ni] = *(const bf16x8*)&Bs[cur][(wc * 64 + ni * 16 + q16) * 32 + 8 * g];
#pragma unroll
        for (int mi = 0; mi < 4; ++mi)
#pragma unroll
            for (int ni = 0; ni < 4; ++ni)
                acc[mi][ni] = mfma16(af[mi], bfr[ni], acc[mi][ni]);
        __syncthreads();
        cur ^= 1;
    }

#pragma unroll
    for (int mi = 0; mi < 4; ++mi) {
#pragma unroll
        for (int ni = 0; ni < 4; ++ni) {
            const int n = nbase + wc * 64 + ni * 16 + q16;
            const float bv = bias[n];
#pragma unroll
            for (int r = 0; r < 4; ++r) {
                const int m = mbase + wr * 64 + mi * 16 + 4 * g + r;
                const float val = acc[mi][ni][r] + bv;
                if (MODE == 0) {
                    const int which = n >> 10, rem = n & 1023;
                    const int h = rem >> 6, d = rem & 63;
                    const int b = m >> 11, t = m & 2047;
                    const long bh = (long)(b * HH + h);
                    if (which == 0)
                        qb[(bh * TT + t) * DD + d] = f2bf(val * 0.125f);
                    else if (which == 1)
                        kb[(bh * TT + t) * DD + d] = f2bf(val);
                    else
                        vtb[(bh * DD + d) * TT + t] = f2bf(val);
                } else {
                    outf[(long)m * N + n] = val;
                }
            }
        }
    }
}

// ---------------- causal flash attention ----------------
// grid: (T/64, B*H), block 256 (4 waves); wave owns 16 q-rows.
// Q pre-scaled by 1/8. Layouts: Q,K = [BH][T][D], V^T = [BH][D][T], out = [B,T,H,D]
__global__ __launch_bounds__(256, 4) void attn_fwd(
    const unsigned short* __restrict__ qb, const unsigned short* __restrict__ kb,
    const unsigned short* __restrict__ vtb, unsigned short* __restrict__ attb) {
    __shared__ unsigned short plds[4][16][32];
    const int tid = threadIdx.x;
    const int w = tid >> 6, lane = tid & 63;
    const int g = lane >> 4, q16 = lane & 15;
    const int bh = blockIdx.y;
    const int b = bh >> 4, h = bh & 15;
    const int qbase = blockIdx.x * 64 + w * 16;

    const unsigned short* Q = qb + (long)bh * TT * DD;
    const unsigned short* Kp = kb + (long)bh * TT * DD;
    const unsigned short* Vt = vtb + (long)bh * DD * TT;

    bf16x8 aq0 = *(const bf16x8*)&Q[(qbase + q16) * DD + 8 * g];
    bf16x8 aq1 = *(const bf16x8*)&Q[(qbase + q16) * DD + 32 + 8 * g];

    f32x4 acc[4];
#pragma unroll
    for (int i = 0; i < 4; ++i) acc[i] = (f32x4){0.f, 0.f, 0.f, 0.f};
    float mrow[4], lrow[4];
#pragma unroll
    for (int r = 0; r < 4; ++r) { mrow[r] = -1e30f; lrow[r] = 0.f; }

    const int nkt = (qbase + 16 + 31) >> 5;  // 32-key tiles needed
    for (int kt = 0; kt < nkt; ++kt) {
        const int kbase = kt * 32;
        f32x4 p0 = {0.f, 0.f, 0.f, 0.f}, p1 = {0.f, 0.f, 0.f, 0.f};
        {
            bf16x8 bk;
            bk = *(const bf16x8*)&Kp[(kbase + q16) * DD + 8 * g];
            p0 = mfma16(aq0, bk, p0);
            bk = *(const bf16x8*)&Kp[(kbase + q16) * DD + 32 + 8 * g];
            p0 = mfma16(aq1, bk, p0);
            bk = *(const bf16x8*)&Kp[(kbase + 16 + q16) * DD + 8 * g];
            p1 = mfma16(aq0, bk, p1);
            bk = *(const bf16x8*)&Kp[(kbase + 16 + q16) * DD + 32 + 8 * g];
            p1 = mfma16(aq1, bk, p1);
        }
        if (kbase + 31 > qbase) {  // boundary tiles: causal mask
#pragma unroll
            for (int r = 0; r < 4; ++r) {
                const int q = qbase + 4 * g + r;
                if (kbase + q16 > q) p0[r] = -1e30f;
                if (kbase + 16 + q16 > q) p1[r] = -1e30f;
            }
        }
        float fs[4];
#pragma unroll
        for (int r = 0; r < 4; ++r) {
            float t0 = fmaxf(p0[r], p1[r]);
            t0 = fmaxf(t0, __shfl_xor(t0, 1));
            t0 = fmaxf(t0, __shfl_xor(t0, 2));
            t0 = fmaxf(t0, __shfl_xor(t0, 4));
            t0 = fmaxf(t0, __shfl_xor(t0, 8));
            const float nm = fmaxf(mrow[r], t0);
            fs[r] = __expf(mrow[r] - nm);
            mrow[r] = nm;
            p0[r] = __expf(p0[r] - nm);
            p1[r] = __expf(p1[r] - nm);
            float s = p0[r] + p1[r];
            s += __shfl_xor(s, 1);
            s += __shfl_xor(s, 2);
            s += __shfl_xor(s, 4);
            s += __shfl_xor(s, 8);
            lrow[r] = lrow[r] * fs[r] + s;
        }
#pragma unroll
        for (int ni = 0; ni < 4; ++ni)
#pragma unroll
            for (int r = 0; r < 4; ++r) acc[ni][r] *= fs[r];
        // P -> LDS (re-layout for PV A-fragment)
#pragma unroll
        for (int r = 0; r < 4; ++r) {
            plds[w][4 * g + r][q16] = f2bf(p0[r]);
            plds[w][4 * g + r][16 + q16] = f2bf(p1[r]);
        }
        bf16x8 pa = *(const bf16x8*)&plds[w][q16][8 * g];
#pragma unroll
        for (int ni = 0; ni < 4; ++ni) {
            bf16x8 bv = *(const bf16x8*)&Vt[(ni * 16 + q16) * TT + kbase + 8 * g];
            acc[ni] = mfma16(pa, bv, acc[ni]);
        }
    }
#pragma unroll
    for (int ni = 0; ni < 4; ++ni)
#pragma unroll
        for (int r = 0; r < 4; ++r) {
            const int q = qbase + 4 * g + r;
            const int d = ni * 16 + q16;
            attb[(((long)b * TT + q) * HH + h) * DD + d] =
                f2bf(acc[ni][r] / lrow[r]);
        }
}

extern "C" void kernel_launch(void* const* d_in, const int* in_sizes, int n_in,
                              void* d_out, int out_size, void* d_ws, size_t ws_size,
                              hipStream_t stream) {
    const float* x = (const float*)d_in[0];
    const float* Wqkv = (const float*)d_in[1];
    const float* bqkv = (const float*)d_in[2];
    const float* Wproj = (const float*)d_in[3];
    const float* bproj = (const float*)d_in[4];
    float* out = (float*)d_out;

    char* ws = (char*)d_ws;
    unsigned short* xb = (unsigned short*)(ws);                  // 16 MB (reused as attb)
    unsigned short* wqkvb = (unsigned short*)(ws + (16l << 20)); // 6 MB
    unsigned short* wprojb = (unsigned short*)(ws + (22l << 20));// 2 MB
    unsigned short* qb = (unsigned short*)(ws + (24l << 20));    // 16 MB
    unsigned short* kb = (unsigned short*)(ws + (40l << 20));    // 16 MB
    unsigned short* vtb = (unsigned short*)(ws + (56l << 20));   // 16 MB -> total 72 MB
    unsigned short* attb = xb;  // x dead after QKV GEMM; reuse

    cvt_bf16<<<2048, 256, 0, stream>>>(x, xb, (long)BB * TT * CC);
    cvt_bf16<<<2048, 256, 0, stream>>>(Wqkv, wqkvb, (long)3 * CC * CC);
    cvt_bf16<<<1024, 256, 0, stream>>>(Wproj, wprojb, (long)CC * CC);

    gemm_bt<0><<<dim3(64, 24), 256, 0, stream>>>(xb, wqkvb, bqkv, qb, kb, vtb,
                                                 nullptr, BB * TT, 3 * CC, CC);
    attn_fwd<<<dim3(TT / 64, BB * HH), 256, 0, stream>>>(qb, kb, vtb, attb);
    gemm_bt<1><<<dim3(64, 8), 256, 0, stream>>>(attb, wprojb, bproj, nullptr,
                                                nullptr, nullptr, out, BB * TT,
                                                CC, CC);
}